// Round 14
// baseline (147.742 us; speedup 1.0000x reference)
//
#include <hip/hip_runtime.h>
#include <cstdint>
#include <cstddef>

#define B_ 8
#define S_ 1024
#define E_ 1024
#define H_ 16
#define D_ 64
#define M_ (B_*S_)

typedef _Float16 f16;
typedef __attribute__((ext_vector_type(8))) _Float16 f16x8;
typedef __attribute__((ext_vector_type(4))) _Float16 f16x4;
typedef __attribute__((ext_vector_type(4))) float  f32x4;
typedef __attribute__((ext_vector_type(16))) float f32x16;
typedef __attribute__((ext_vector_type(4))) int    int4v;
typedef __attribute__((ext_vector_type(2))) int    int2v;

__device__ __forceinline__ f32x4 mfma16(f16x8 a, f16x8 b, f32x4 c) {
  return __builtin_amdgcn_mfma_f32_16x16x32_f16(a, b, c, 0, 0, 0);
}
__device__ __forceinline__ f32x16 mfma32(f16x8 a, f16x8 b, f32x16 c) {
  return __builtin_amdgcn_mfma_f32_32x32x16_f16(a, b, c, 0, 0, 0);
}
__device__ __forceinline__ void gll16(const f16* g, f16* l) {
  __builtin_amdgcn_global_load_lds(
      (const __attribute__((address_space(1))) void*)g,
      (__attribute__((address_space(3))) void*)l, 16, 0, 0);
}
__device__ __forceinline__ int pkrtz(float lo, float hi) {
  return __builtin_bit_cast(int, __builtin_amdgcn_cvt_pkrtz(lo, hi));
}

// ---------------------------------------------------------------------------
// X fp32 -> fp16
// ---------------------------------------------------------------------------
__global__ __launch_bounds__(256) void presplit_kernel(
    const float* __restrict__ X, f16* __restrict__ Xf) {
  size_t i = ((size_t)blockIdx.x * 256 + threadIdx.x) * 8;
  f32x4 v0 = *(const f32x4*)&X[i];
  f32x4 v1 = *(const f32x4*)&X[i + 4];
  f16x8 hv;
#pragma unroll
  for (int j = 0; j < 4; ++j) {
    hv[j] = (f16)v0[j];
    hv[j + 4] = (f16)v1[j];
  }
  *(f16x8*)&Xf[i] = hv;
}

// ---------------------------------------------------------------------------
// Transpose + convert weights -> single fp16, [f][e] layout.
// W_Q pre-scaled by log2(e) (softmax runs in exp2 domain).
// ---------------------------------------------------------------------------
__global__ __launch_bounds__(512) void wt_conv3_kernel(
    const float* __restrict__ Wq, const float* __restrict__ Wk,
    const float* __restrict__ Wv, f16* __restrict__ oq, f16* __restrict__ ok,
    f16* __restrict__ ov) {
  const float* W = blockIdx.z == 0 ? Wq : (blockIdx.z == 1 ? Wk : Wv);
  f16* o = blockIdx.z == 0 ? oq : (blockIdx.z == 1 ? ok : ov);
  const float scl = blockIdx.z == 0 ? 1.4426950408889634f : 1.0f;
  __shared__ float t[64][65];
  const int f0 = blockIdx.x * 64, e0 = blockIdx.y * 64;
  const int tx = threadIdx.x, ty = threadIdx.y;
#pragma unroll
  for (int j = 0; j < 8; ++j)
    t[ty + 8 * j][tx] = W[(size_t)(e0 + ty + 8 * j) * E_ + f0 + tx];
  __syncthreads();
#pragma unroll
  for (int j = 0; j < 8; ++j)
    o[(size_t)(f0 + ty + 8 * j) * E_ + e0 + tx] =
        (f16)(t[tx][ty + 8 * j] * scl);
}

// ---------------------------------------------------------------------------
// Fused QKV GEMM — 256x256 tile, BK=64, 8 waves (512 thr), 4-phase/K-tile
// schedule with counted vmcnt (m201-template adaptation).
// LDS: sA[2][256][64] + sB[2][256][64] = 128 KB (1 block/CU).
// Per K-tile k (slot k&1), quadrant phases q0..q3 (16 mfma16 each):
//   q0: read all B-frags + A-quad0; stage A(k+1).h0
//   q1: A-quad1; stage A(k+1).h1;  [barrier]
//   q2: A-quad2; stage B(k+2).h0
//   q3: A-quad3; stage B(k+2).h1;  vmcnt(4) [k=14: vmcnt(0)]; [barrier]
// Hazards: B(k) last ds_read at q0 < q1-barrier < B(k+2) stage at q2;
// A(k-1) freed at prior tile's end barrier; in-order vmcnt(4) at tile end
// forces A(k+1)+B(k+1) landed, leaves B(k+2)'s 4 loads in flight.
// z: nt 0-3 = Q (log2e-scaled), 4-7 = K, 8-11 = V (transposed [B,H,D,S]).
// ---------------------------------------------------------------------------
__global__ __launch_bounds__(512) void gemm_qkv8_kernel(
    const f16* __restrict__ Xf,
    const f16* __restrict__ Wq, const f16* __restrict__ Wk,
    const f16* __restrict__ Wv,
    f16* __restrict__ Qf, f16* __restrict__ Kf, f16* __restrict__ Vt) {
  __shared__ f16 sA[2][256][64], sB[2][256][64];   // 128 KB
  const int bid = blockIdx.x;
  const int xcd = bid & 7, idx = bid >> 3;   // 48 blocks per XCD chunk
  const int mb = xcd * 4 + idx / 12;         // [0,32)
  const int nt = idx % 12;
  const int z = nt >> 2;
  const int m0 = mb * 256;
  const int n0 = (nt & 3) * 256;
  const f16* __restrict__ Bt = z == 0 ? Wq : (z == 1 ? Wk : Wv);
  const int tid = threadIdx.x;
  const int lane = tid & 63, w = tid >> 6;
  const int wr = (w >> 2) * 128, wc = (w & 3) * 64;
  const int fr = lane & 15, fg = lane >> 4;

  f32x4 acc[8][4] = {};

#define GS_A(slot, kt, hh)                                                    \
  { _Pragma("unroll") for (int j = 0; j < 2; ++j) {                           \
      int ci = tid + j * 512;                                                 \
      int r = ci >> 3, cl = ci & 7;                                           \
      int cs = (cl ^ (r & 7)) * 8;                                            \
      gll16(Xf + (size_t)(m0 + (hh) * 128 + r) * E_ + (kt) * 64 + cs,         \
            &sA[slot][(hh) * 128][0] + ci * 8); } }
#define GS_B(slot, kt, hh)                                                    \
  { _Pragma("unroll") for (int j = 0; j < 2; ++j) {                           \
      int ci = tid + j * 512;                                                 \
      int r = ci >> 3, cl = ci & 7;                                           \
      int cs = (cl ^ (r & 7)) * 8;                                            \
      gll16(Bt + (size_t)(n0 + (hh) * 128 + r) * E_ + (kt) * 64 + cs,         \
            &sB[slot][(hh) * 128][0] + ci * 8); } }
#define RD_B(slot)                                                            \
  { _Pragma("unroll") for (int ni = 0; ni < 4; ++ni)                          \
      _Pragma("unroll") for (int ks = 0; ks < 2; ++ks) {                      \
        int rB = wc + ni * 16 + fr;                                           \
        bf[ni][ks] =                                                          \
            *(const f16x8*)&sB[slot][rB][(((ks * 4 + fg) ^ (rB & 7))) * 8]; } }
#define RD_A2(slot, q)                                                        \
  { _Pragma("unroll") for (int dm = 0; dm < 2; ++dm)                          \
      _Pragma("unroll") for (int ks = 0; ks < 2; ++ks) {                      \
        int rA = wr + ((q) * 2 + dm) * 16 + fr;                               \
        af[dm][ks] =                                                          \
            *(const f16x8*)&sA[slot][rA][(((ks * 4 + fg) ^ (rA & 7))) * 8]; } }
#define MMQ(q)                                                                \
  { __builtin_amdgcn_s_setprio(1);                                            \
    _Pragma("unroll") for (int ni = 0; ni < 4; ++ni)                          \
      _Pragma("unroll") for (int ks = 0; ks < 2; ++ks)                        \
        _Pragma("unroll") for (int dm = 0; dm < 2; ++dm)                      \
          acc[(q) * 2 + dm][ni] =                                             \
              mfma16(af[dm][ks], bf[ni][ks], acc[(q) * 2 + dm][ni]);          \
    __builtin_amdgcn_s_setprio(0); }
#define GBAR()                                                                \
  { __builtin_amdgcn_sched_barrier(0);                                        \
    __builtin_amdgcn_s_barrier();                                             \
    __builtin_amdgcn_sched_barrier(0); }

  // prologue: A(0).h0,h1  B(0).h0,h1  B(1).h0,h1 ; need first 8 loads done
  GS_A(0, 0, 0); GS_A(0, 0, 1);
  GS_B(0, 0, 0); GS_B(0, 0, 1);
  GS_B(1, 1, 0); GS_B(1, 1, 1);
  asm volatile("s_waitcnt vmcnt(4)" ::: "memory");
  GBAR();

  for (int k = 0; k < 16; ++k) {
    const int slot = k & 1;
    f16x8 bf[4][2], af[2][2];
    // q0
    RD_B(slot);
    RD_A2(slot, 0);
    if (k < 15) GS_A(slot ^ 1, k + 1, 0);
    MMQ(0);
    // q1
    RD_A2(slot, 1);
    if (k < 15) GS_A(slot ^ 1, k + 1, 1);
    MMQ(1);
    GBAR();   // all waves done reading B(k) before B(k+2) staging below
    // q2
    RD_A2(slot, 2);
    if (k < 14) GS_B(slot, k + 2, 0);
    MMQ(2);
    // q3
    RD_A2(slot, 3);
    if (k < 14) GS_B(slot, k + 2, 1);
    MMQ(3);
    if (k < 14) {
      asm volatile("s_waitcnt vmcnt(4)" ::: "memory");   // A(k+1),B(k+1) landed
    } else {
      asm volatile("s_waitcnt vmcnt(0)" ::: "memory");   // tail drain
    }
    GBAR();
  }

  // epilogue
  if (z < 2) {
    f16* Of = z == 0 ? Qf : Kf;
#pragma unroll
    for (int mi = 0; mi < 8; ++mi)
#pragma unroll
      for (int ni = 0; ni < 4; ++ni)
#pragma unroll
        for (int r = 0; r < 4; ++r) {
          int row = m0 + wr + mi * 16 + fg * 4 + r;
          int col = n0 + wc + ni * 16 + fr;
          int bb = row >> 10, s = row & 1023;
          int hd = col >> 6, d = col & 63;
          Of[((size_t)(bb * H_ + hd) * S_ + s) * D_ + d] = (f16)acc[mi][ni][r];
        }
  } else {
#pragma unroll
    for (int mi = 0; mi < 8; ++mi)
#pragma unroll
      for (int ni = 0; ni < 4; ++ni) {
        int row = m0 + wr + mi * 16 + fg * 4;
        int col = n0 + wc + ni * 16 + fr;
        int bb = row >> 10, s = row & 1023;
        int hd = col >> 6, d = col & 63;
        f16x4 p;
#pragma unroll
        for (int r = 0; r < 4; ++r) p[r] = (f16)acc[mi][ni][r];
        *(f16x4*)&Vt[((size_t)(bb * H_ + hd) * D_ + d) * S_ + s] = p;
      }
  }
#undef GS_A
#undef GS_B
#undef RD_B
#undef RD_A2
#undef MMQ
#undef GBAR
}

// ---------------------------------------------------------------------------
// Flash attention + ReLU — round-11 version (known-good, ~55 us).
// 1-term fp16 QK^T; MFMA rowsum (Ol); 2-phase LDS (32KB), STAGE(t+1) at
// iter top, vmcnt(0)+barrier at iter end; 4 blocks/CU (grid 1024);
// exact-max chunk-0 prologue (overflow-safe), spec-exp2 + rare rescale.
// ---------------------------------------------------------------------------
__global__ __launch_bounds__(256, 4) void attn_kernel(
    const f16* __restrict__ Qf, const f16* __restrict__ Kf,
    const f16* __restrict__ Vt, float* __restrict__ out) {
  __shared__ f16 sK[2][64][64], sV[2][64][64];   // 32 KB
  const int bid = blockIdx.x;
  const int bh = (bid & 7) * 16 + (bid >> 6);    // 8 qb of one bh on one XCD
  const int qb = (bid >> 3) & 7;
  const int hd = bh & 15, bb = bh >> 4;
  const int tid = threadIdx.x;
  const int lane = tid & 63, w = tid >> 6;
  const int cq = lane & 31, h = lane >> 5;
  const int rsw = cq & 7;
  const size_t base = (size_t)bh * (S_ * D_);
  const f16* Qf_p = Qf + base;
  const f16* Kf_p = Kf + base;
  const f16* Vt_p = Vt + base;
  const int q0 = qb * 128 + w * 32;

  f16x8 qh_[4];
#pragma unroll
  for (int ks = 0; ks < 4; ++ks)
    qh_[ks] = *(const f16x8*)&Qf_p[(size_t)(q0 + cq) * D_ + ks * 16 + 8 * h];

  f16x8 ones;
#pragma unroll
  for (int j = 0; j < 8; ++j) ones[j] = (f16)1.0f;

  float m_run;
  f32x16 O[2] = {}, Ol = {};     // Ol: all-ones-A mfma rowsum (l = Ol[0])
  f16x8 pf[4];

#define STAGE(buf, kb)                                                        \
  {                                                                           \
    _Pragma("unroll")                                                         \
    for (int half = 0; half < 2; ++half) {                                    \
      int ci = tid + half * 256;                                              \
      int row = ci >> 3, cl = ci & 7;                                         \
      int cs = cl ^ (row & 7);                                                \
      gll16(Kf_p + (size_t)((kb) + row) * D_ + cs * 8, &sK[buf][0][0] + ci * 8); \
      gll16(Vt_p + (size_t)row * S_ + (kb) + cs * 8, &sV[buf][0][0] + ci * 8);   \
    }                                                                         \
  }

#define QKT(scv, bufi)                                                        \
  {                                                                           \
    _Pragma("unroll")                                                         \
    for (int f = 0; f < 2; ++f) {                                             \
      _Pragma("unroll")                                                       \
      for (int ks = 0; ks < 4; ++ks) {                                        \
        int cc = ((2 * ks + h) ^ rsw) * 8;                                    \
        f16x8 kv = *(const f16x8*)&sK[bufi][f * 32 + cq][cc];                 \
        scv[f] = mfma32(kv, qh_[ks], scv[f]);                                 \
      }                                                                       \
    }                                                                         \
  }

#define MAXTREE(pm, scv)                                                      \
  {                                                                           \
    float t4[4];                                                              \
    _Pragma("unroll")                                                         \
    for (int i = 0; i < 4; ++i) {                                             \
      float a = fmaxf(fmaxf(scv[0][i], scv[0][i + 4]),                        \
                      fmaxf(scv[0][i + 8], scv[0][i + 12]));                  \
      float b = fmaxf(fmaxf(scv[1][i], scv[1][i + 4]),                        \
                      fmaxf(scv[1][i + 8], scv[1][i + 12]));                  \
      t4[i] = fmaxf(a, b);                                                    \
    }                                                                         \
    pm = fmaxf(fmaxf(t4[0], t4[1]), fmaxf(t4[2], t4[3]));                     \
    pm = fmaxf(pm, __shfl_xor(pm, 32));                                       \
  }

#define PFBUILD(scv)                                                          \
  {                                                                           \
    _Pragma("unroll")                                                         \
    for (int f = 0; f < 2; ++f) {                                             \
      _Pragma("unroll")                                                       \
      for (int ksl = 0; ksl < 2; ++ksl) {                                     \
        int b0 = 8 * ksl;                                                     \
        int a1 = pkrtz(scv[f][b0 + 0], scv[f][b0 + 1]);                       \
        int b1 = pkrtz(scv[f][b0 + 4], scv[f][b0 + 5]);                       \
        int2v r1 = __builtin_amdgcn_permlane32_swap(a1, b1, false, false);    \
        int a2 = pkrtz(scv[f][b0 + 2], scv[f][b0 + 3]);                       \
        int b2 = pkrtz(scv[f][b0 + 6], scv[f][b0 + 7]);                       \
        int2v r2 = __builtin_amdgcn_permlane32_swap(a2, b2, false, false);    \
        int4v wd;                                                             \
        wd[0] = r1[0]; wd[1] = r2[0]; wd[2] = r1[1]; wd[3] = r2[1];           \
        pf[2 * f + ksl] = __builtin_bit_cast(f16x8, wd);                      \
      }                                                                       \
    }                                                                         \
  }

#define PVT(bufi)                                                             \
  {                                                                           \
    _Pragma("unroll")                                                         \
    for (int ks = 0; ks < 4; ++ks) {                                          \
      int cc = ((2 * ks + h) ^ rsw) * 8;                                      \
      _Pragma("unroll")                                                       \
      for (int df = 0; df < 2; ++df) {                                        \
        f16x8 vf = *(const f16x8*)&sV[bufi][df * 32 + cq][cc];                \
        O[df] = mfma32(vf, pf[ks], O[df]);                                    \
      }                                                                       \
      Ol = mfma32(ones, pf[ks], Ol);                                          \
    }                                                                         \
  }

  // ---- prologue: stage + compute chunk 0 with EXACT max (overflow-safe)
  STAGE(0, 0);
  asm volatile("s_waitcnt vmcnt(0)" ::: "memory");
  __builtin_amdgcn_sched_barrier(0);
  __builtin_amdgcn_s_barrier();
  STAGE(1, 64);                        // prefetch chunk 1 under chunk-0 work
  {
    f32x16 sc[2] = {};
    __builtin_amdgcn_s_setprio(1);
    QKT(sc, 0);
    __builtin_amdgcn_s_setprio(0);
    float pm;
    MAXTREE(pm, sc);
    m_run = pm;
#pragma unroll
    for (int f = 0; f < 2; ++f)
#pragma unroll
      for (int r = 0; r < 16; ++r)
        sc[f][r] = __builtin_amdgcn_exp2f(sc[f][r] - pm);
    PFBUILD(sc);
    __builtin_amdgcn_s_setprio(1);
    PVT(0);
    __builtin_amdgcn_s_setprio(0);
  }
  asm volatile("s_waitcnt vmcnt(0)" ::: "memory");
  __builtin_amdgcn_sched_barrier(0);
  __builtin_amdgcn_s_barrier();

  // ---- main loop, chunks 1..15: spec-exp + rare exact rescale
  for (int t = 1; t < 16; ++t) {
    const int cur = t & 1;
    if (t < 15) STAGE(cur ^ 1, (t + 1) * 64);   // hides under compute(t)

    f32x16 sc[2];
#pragma unroll
    for (int f = 0; f < 2; ++f)
#pragma unroll
      for (int r = 0; r < 16; ++r) sc[f][r] = -m_run;
    __builtin_amdgcn_s_setprio(1);
    QKT(sc, cur);
    __builtin_amdgcn_s_setprio(0);

#pragma unroll
    for (int f = 0; f < 2; ++f)
#pragma unroll
      for (int r = 0; r < 16; ++r)
        sc[f][r] = __builtin_amdgcn_exp2f(sc[f][r]);

    float pm;
    MAXTREE(pm, sc);
    if (__any(pm > 2048.f)) {
      float pmx = fmaxf(pm, 1.0f);
      float scl = 1.0f / pmx;
      m_run += __builtin_amdgcn_logf(pmx);   // v_log_f32 = log2
#pragma unroll
      for (int f = 0; f < 2; ++f)
#pragma unroll
        for (int r = 0; r < 16; ++r) sc[f][r] *= scl;
#pragma unroll
      for (int df = 0; df < 2; ++df)
#pragma unroll
        for (int i = 0; i < 16; ++i) O[df][i] *= scl;
#pragma unroll
      for (int i = 0; i < 16; ++i) Ol[i] *= scl;
    }

    PFBUILD(sc);
    __builtin_amdgcn_s_setprio(1);
    PVT(cur);
    __builtin_amdgcn_s_setprio(0);

    asm volatile("s_waitcnt vmcnt(0)" ::: "memory");
    __builtin_amdgcn_sched_barrier(0);
    __builtin_amdgcn_s_barrier();
  }

  // ---- epilogue: relu(O/l) -> fp32 [B,S,E];  l = Ol[0] (all rows equal)
  float inv = 1.0f / Ol[0];
  int s = q0 + cq;
  float* orow = out + ((size_t)bb * S_ + s) * E_ + hd * 64;
#pragma unroll
  for (int df = 0; df < 2; ++df)
#pragma unroll
    for (int g = 0; g < 4; ++g) {
      f32x4 vv;
#pragma unroll
      for (int j = 0; j < 4; ++j)
        vv[j] = fmaxf(O[df][4 * g + j] * inv, 0.f);
      *(f32x4*)&orow[df * 32 + 8 * g + 4 * h] = vv;
    }
}

// ---------------------------------------------------------------------------
// Launcher. Workspace ~70 MB:
//  Wq,Wk,Wv 3x2MB @0; Xf @6M; Qf @22M; Kf @38M; Vt @54M
// ---------------------------------------------------------------------------
extern "C" void kernel_launch(void* const* d_in, const int* in_sizes, int n_in,
                              void* d_out, int out_size, void* d_ws, size_t ws_size,
                              hipStream_t stream) {
  const float* X  = (const float*)d_in[0];
  const float* Wq = (const float*)d_in[1];
  const float* Wk = (const float*)d_in[2];
  const float* Wv = (const float*)d_in[3];
  float* out = (float*)d_out;
  char* ws = (char*)d_ws;

  const size_t WSZ = (size_t)E_ * E_ * sizeof(f16);   // 2 MB
  const size_t QSZ = (size_t)M_ * E_ * sizeof(f16);   // 16 MB
  f16* Wqf = (f16*)(ws);
  f16* Wkf = (f16*)(ws + WSZ);
  f16* Wvf = (f16*)(ws + 2 * WSZ);
  char* p = ws + 3 * WSZ;
  f16* Xf = (f16*)(p);
  f16* Qf = (f16*)(p + QSZ);
  f16* Kf = (f16*)(p + 2 * QSZ);
  f16* Vt = (f16*)(p + 3 * QSZ);

  presplit_kernel<<<4096, 256, 0, stream>>>(X, Xf);
  wt_conv3_kernel<<<dim3(16, 16, 3), dim3(64, 8), 0, stream>>>(
      Wq, Wk, Wv, Wqf, Wkf, Wvf);

  gemm_qkv8_kernel<<<384, 512, 0, stream>>>(
      Xf, Wqf, Wkf, Wvf, Qf, Kf, Vt);

  attn_kernel<<<1024, 256, 0, stream>>>(Qf, Kf, Vt, out);
}

// Round 15
// 133.494 us; speedup vs baseline: 1.1067x; 1.1067x over previous
//
#include <hip/hip_runtime.h>
#include <cstdint>
#include <cstddef>

#define B_ 8
#define S_ 1024
#define E_ 1024
#define H_ 16
#define D_ 64
#define M_ (B_*S_)

typedef _Float16 f16;
typedef __attribute__((ext_vector_type(8))) _Float16 f16x8;
typedef __attribute__((ext_vector_type(4))) _Float16 f16x4;
typedef __attribute__((ext_vector_type(4))) float  f32x4;
typedef __attribute__((ext_vector_type(16))) float f32x16;
typedef __attribute__((ext_vector_type(4))) int    int4v;
typedef __attribute__((ext_vector_type(2))) int    int2v;

__device__ __forceinline__ f32x4 mfma16(f16x8 a, f16x8 b, f32x4 c) {
  return __builtin_amdgcn_mfma_f32_16x16x32_f16(a, b, c, 0, 0, 0);
}
__device__ __forceinline__ f32x16 mfma32(f16x8 a, f16x8 b, f32x16 c) {
  return __builtin_amdgcn_mfma_f32_32x32x16_f16(a, b, c, 0, 0, 0);
}
__device__ __forceinline__ void gll16(const f16* g, f16* l) {
  __builtin_amdgcn_global_load_lds(
      (const __attribute__((address_space(1))) void*)g,
      (__attribute__((address_space(3))) void*)l, 16, 0, 0);
}
__device__ __forceinline__ int pkrtz(float lo, float hi) {
  return __builtin_bit_cast(int, __builtin_amdgcn_cvt_pkrtz(lo, hi));
}

// ---------------------------------------------------------------------------
// Merged prepass: blocks 0..4095 convert X fp32->fp16 (8 elems/thread);
// blocks 4096..4863 transpose+convert one 64x64 weight tile
// (W_Q pre-scaled by log2(e): softmax runs in the exp2 domain).
// ---------------------------------------------------------------------------
__global__ __launch_bounds__(256) void prep_kernel(
    const float* __restrict__ X, const float* __restrict__ Wq,
    const float* __restrict__ Wk, const float* __restrict__ Wv,
    f16* __restrict__ Xf, f16* __restrict__ oq, f16* __restrict__ ok,
    f16* __restrict__ ov) {
  __shared__ float t[64][65];
  const int bid = blockIdx.x;
  if (bid < 4096) {
    size_t i = ((size_t)bid * 256 + threadIdx.x) * 8;
    f32x4 v0 = *(const f32x4*)&X[i];
    f32x4 v1 = *(const f32x4*)&X[i + 4];
    f16x8 hv;
#pragma unroll
    for (int j = 0; j < 4; ++j) {
      hv[j] = (f16)v0[j];
      hv[j + 4] = (f16)v1[j];
    }
    *(f16x8*)&Xf[i] = hv;
    return;
  }
  const int wid = bid - 4096;
  const int which = wid >> 8, tile = wid & 255;
  const float* W = which == 0 ? Wq : (which == 1 ? Wk : Wv);
  f16* o = which == 0 ? oq : (which == 1 ? ok : ov);
  const float scl = which == 0 ? 1.4426950408889634f : 1.0f;
  const int f0 = (tile & 15) * 64, e0 = (tile >> 4) * 64;
  const int tx = threadIdx.x & 63, tyy = threadIdx.x >> 6;
#pragma unroll
  for (int j = 0; j < 16; ++j) {
    int row = 4 * j + tyy;
    t[row][tx] = W[(size_t)(e0 + row) * E_ + f0 + tx];
  }
  __syncthreads();
#pragma unroll
  for (int j = 0; j < 16; ++j) {
    int row = 4 * j + tyy;
    o[(size_t)(f0 + row) * E_ + e0 + tx] = (f16)(t[tx][row] * scl);
  }
}

// ---------------------------------------------------------------------------
// Fused QKV GEMM: O = X(f16) * W(f16).  Round-11 single-buffered version
// (measured 65.4 us / ~790 TF — the m97-structure ceiling for this shape;
// both deeper-pipeline attempts (r13 2-phase, r14 256^2 4-phase) regressed:
// grid quantization + lost co-residency dominate at this problem size).
// z: 0-7 = Q ([B,H,S,D], log2e-scaled), 8-15 = K, 16-23 = V ([B,H,D,S]).
// ---------------------------------------------------------------------------
__global__ __launch_bounds__(256) void gemm_qkv_kernel(
    const f16* __restrict__ Xf,
    const f16* __restrict__ Wq, const f16* __restrict__ Wk,
    const f16* __restrict__ Wv,
    f16* __restrict__ Qf, f16* __restrict__ Kf, f16* __restrict__ Vt) {
  __shared__ f16 sA[128][64], sB[128][64];   // 32 KB
  const int bid = blockIdx.x;
  const int xcd = bid & 7, idx = bid >> 3;   // idx in [0,192)
  const int mb = xcd * 8 + idx / 24;         // [0,64)
  const int nb = idx % 24;
  const int z = nb >> 3;
  const int n0 = (nb & 7) * 128, m0 = mb * 128;
  const f16* __restrict__ Bt = z == 0 ? Wq : (z == 1 ? Wk : Wv);
  const int tid = threadIdx.x;
  const int lane = tid & 63, w = tid >> 6;
  const int wm = (w >> 1) * 64, wn = (w & 1) * 64;
  const int fr = lane & 15, fg = lane >> 4;
  f32x4 acc[4][4] = {};
  for (int k0 = 0; k0 < E_; k0 += 64) {
#pragma unroll
    for (int i = 0; i < 4; ++i) {
      int ci = tid + i * 256;
      int r = ci >> 3, cl = ci & 7;
      int cs = (cl ^ (r & 7)) * 8;       // pre-swizzled global source column
      gll16(Xf + (size_t)(m0 + r) * E_ + k0 + cs, &sA[0][0] + ci * 8);
      gll16(Bt + (size_t)(n0 + r) * E_ + k0 + cs, &sB[0][0] + ci * 8);
    }
    __syncthreads();
#pragma unroll
    for (int kh2 = 0; kh2 < 2; ++kh2) {
      f16x8 ah[4];
#pragma unroll
      for (int mi = 0; mi < 4; ++mi) {
        int rA = wm + mi * 16 + fr;
        ah[mi] = *(const f16x8*)&sA[rA][(((kh2 * 4 + fg) ^ (rA & 7))) * 8];
      }
#pragma unroll
      for (int ni = 0; ni < 4; ++ni) {
        int rB = wn + ni * 16 + fr;
        f16x8 bh = *(const f16x8*)&sB[rB][(((kh2 * 4 + fg) ^ (rB & 7))) * 8];
#pragma unroll
        for (int mi = 0; mi < 4; ++mi)
          acc[mi][ni] = mfma16(ah[mi], bh, acc[mi][ni]);
      }
    }
    __syncthreads();
  }
  if (z < 2) {
    f16* Of = z == 0 ? Qf : Kf;
#pragma unroll
    for (int mi = 0; mi < 4; ++mi)
#pragma unroll
      for (int ni = 0; ni < 4; ++ni)
#pragma unroll
        for (int r = 0; r < 4; ++r) {
          int row = m0 + wm + mi * 16 + (lane >> 4) * 4 + r;
          int col = n0 + wn + ni * 16 + fr;
          int bb = row >> 10, s = row & 1023;
          int hd = col >> 6, d = col & 63;
          Of[((size_t)(bb * H_ + hd) * S_ + s) * D_ + d] = (f16)acc[mi][ni][r];
        }
  } else {
#pragma unroll
    for (int mi = 0; mi < 4; ++mi)
#pragma unroll
      for (int ni = 0; ni < 4; ++ni) {
        int row = m0 + wm + mi * 16 + (lane >> 4) * 4;
        int col = n0 + wn + ni * 16 + fr;
        int bb = row >> 10, s = row & 1023;
        int hd = col >> 6, d = col & 63;
        f16x4 p;
#pragma unroll
        for (int r = 0; r < 4; ++r) p[r] = (f16)acc[mi][ni][r];
        *(f16x4*)&Vt[((size_t)(bb * H_ + hd) * D_ + d) * S_ + s] = p;
      }
  }
}

// ---------------------------------------------------------------------------
// Flash attention + ReLU — round-11 structure, with rowsum moved BACK to the
// VALU (pipe rebalance: MFMA is the heaviest pipe at ~17us/CU; the ones-MFMA
// rowsum added 20% MFMA to save ~1us of VALU).  Everything else identical:
// 1-term fp16 QK^T; 2-phase LDS (32KB), STAGE(t+1) at iter top,
// vmcnt(0)+barrier at iter end; 4 blocks/CU (grid 1024); exact-max chunk-0
// prologue (overflow-safe); spec-exp2 + rare exact rescale.
// ---------------------------------------------------------------------------
__global__ __launch_bounds__(256, 4) void attn_kernel(
    const f16* __restrict__ Qf, const f16* __restrict__ Kf,
    const f16* __restrict__ Vt, float* __restrict__ out) {
  __shared__ f16 sK[2][64][64], sV[2][64][64];   // 32 KB
  const int bid = blockIdx.x;
  const int bh = (bid & 7) * 16 + (bid >> 6);    // 8 qb of one bh on one XCD
  const int qb = (bid >> 3) & 7;
  const int hd = bh & 15, bb = bh >> 4;
  const int tid = threadIdx.x;
  const int lane = tid & 63, w = tid >> 6;
  const int cq = lane & 31, h = lane >> 5;
  const int rsw = cq & 7;
  const size_t base = (size_t)bh * (S_ * D_);
  const f16* Qf_p = Qf + base;
  const f16* Kf_p = Kf + base;
  const f16* Vt_p = Vt + base;
  const int q0 = qb * 128 + w * 32;

  f16x8 qh_[4];
#pragma unroll
  for (int ks = 0; ks < 4; ++ks)
    qh_[ks] = *(const f16x8*)&Qf_p[(size_t)(q0 + cq) * D_ + ks * 16 + 8 * h];

  float m_run, l_run;
  f32x16 O[2] = {};
  f16x8 pf[4];

#define STAGE(buf, kb)                                                        \
  {                                                                           \
    _Pragma("unroll")                                                         \
    for (int half = 0; half < 2; ++half) {                                    \
      int ci = tid + half * 256;                                              \
      int row = ci >> 3, cl = ci & 7;                                         \
      int cs = cl ^ (row & 7);                                                \
      gll16(Kf_p + (size_t)((kb) + row) * D_ + cs * 8, &sK[buf][0][0] + ci * 8); \
      gll16(Vt_p + (size_t)row * S_ + (kb) + cs * 8, &sV[buf][0][0] + ci * 8);   \
    }                                                                         \
  }

#define QKT(scv, bufi)                                                        \
  {                                                                           \
    _Pragma("unroll")                                                         \
    for (int f = 0; f < 2; ++f) {                                             \
      _Pragma("unroll")                                                       \
      for (int ks = 0; ks < 4; ++ks) {                                        \
        int cc = ((2 * ks + h) ^ rsw) * 8;                                    \
        f16x8 kv = *(const f16x8*)&sK[bufi][f * 32 + cq][cc];                 \
        scv[f] = mfma32(kv, qh_[ks], scv[f]);                                 \
      }                                                                       \
    }                                                                         \
  }

#define MAXTREE(pm, scv)                                                      \
  {                                                                           \
    float t4[4];                                                              \
    _Pragma("unroll")                                                         \
    for (int i = 0; i < 4; ++i) {                                             \
      float a = fmaxf(fmaxf(scv[0][i], scv[0][i + 4]),                        \
                      fmaxf(scv[0][i + 8], scv[0][i + 12]));                  \
      float b = fmaxf(fmaxf(scv[1][i], scv[1][i + 4]),                        \
                      fmaxf(scv[1][i + 8], scv[1][i + 12]));                  \
      t4[i] = fmaxf(a, b);                                                    \
    }                                                                         \
    pm = fmaxf(fmaxf(t4[0], t4[1]), fmaxf(t4[2], t4[3]));                     \
    pm = fmaxf(pm, __shfl_xor(pm, 32));                                       \
  }

#define ROWSUM(rs, scv)                                                       \
  {                                                                           \
    float rs0 = 0.f, rs1 = 0.f, rs2 = 0.f, rs3 = 0.f;                         \
    _Pragma("unroll")                                                         \
    for (int f = 0; f < 2; ++f) {                                             \
      _Pragma("unroll")                                                       \
      for (int r4 = 0; r4 < 4; ++r4) {                                        \
        rs0 += scv[f][4 * r4 + 0];                                            \
        rs1 += scv[f][4 * r4 + 1];                                            \
        rs2 += scv[f][4 * r4 + 2];                                            \
        rs3 += scv[f][4 * r4 + 3];                                            \
      }                                                                       \
    }                                                                         \
    rs = (rs0 + rs1) + (rs2 + rs3);                                           \
    rs += __shfl_xor(rs, 32);                                                 \
  }

#define PFBUILD(scv)                                                          \
  {                                                                           \
    _Pragma("unroll")                                                         \
    for (int f = 0; f < 2; ++f) {                                             \
      _Pragma("unroll")                                                       \
      for (int ksl = 0; ksl < 2; ++ksl) {                                     \
        int b0 = 8 * ksl;                                                     \
        int a1 = pkrtz(scv[f][b0 + 0], scv[f][b0 + 1]);                       \
        int b1 = pkrtz(scv[f][b0 + 4], scv[f][b0 + 5]);                       \
        int2v r1 = __builtin_amdgcn_permlane32_swap(a1, b1, false, false);    \
        int a2 = pkrtz(scv[f][b0 + 2], scv[f][b0 + 3]);                       \
        int b2 = pkrtz(scv[f][b0 + 6], scv[f][b0 + 7]);                       \
        int2v r2 = __builtin_amdgcn_permlane32_swap(a2, b2, false, false);    \
        int4v wd;                                                             \
        wd[0] = r1[0]; wd[1] = r2[0]; wd[2] = r1[1]; wd[3] = r2[1];           \
        pf[2 * f + ksl] = __builtin_bit_cast(f16x8, wd);                      \
      }                                                                       \
    }                                                                         \
  }

#define PVT(bufi)                                                             \
  {                                                                           \
    _Pragma("unroll")                                                         \
    for (int ks = 0; ks < 4; ++ks) {                                          \
      int cc = ((2 * ks + h) ^ rsw) * 8;                                      \
      _Pragma("unroll")                                                       \
      for (int df = 0; df < 2; ++df) {                                        \
        f16x8 vf = *(const f16x8*)&sV[bufi][df * 32 + cq][cc];                \
        O[df] = mfma32(vf, pf[ks], O[df]);                                    \
      }                                                                       \
    }                                                                         \
  }

  // ---- prologue: stage + compute chunk 0 with EXACT max (overflow-safe)
  STAGE(0, 0);
  asm volatile("s_waitcnt vmcnt(0)" ::: "memory");
  __builtin_amdgcn_sched_barrier(0);
  __builtin_amdgcn_s_barrier();
  STAGE(1, 64);                        // prefetch chunk 1 under chunk-0 work
  {
    f32x16 sc[2] = {};
    __builtin_amdgcn_s_setprio(1);
    QKT(sc, 0);
    __builtin_amdgcn_s_setprio(0);
    float pm;
    MAXTREE(pm, sc);
    m_run = pm;
#pragma unroll
    for (int f = 0; f < 2; ++f)
#pragma unroll
      for (int r = 0; r < 16; ++r)
        sc[f][r] = __builtin_amdgcn_exp2f(sc[f][r] - pm);
    float rs;
    ROWSUM(rs, sc);
    l_run = rs;
    PFBUILD(sc);
    __builtin_amdgcn_s_setprio(1);
    PVT(0);
    __builtin_amdgcn_s_setprio(0);
  }
  asm volatile("s_waitcnt vmcnt(0)" ::: "memory");
  __builtin_amdgcn_sched_barrier(0);
  __builtin_amdgcn_s_barrier();

  // ---- main loop, chunks 1..15: spec-exp + rare exact rescale
  for (int t = 1; t < 16; ++t) {
    const int cur = t & 1;
    if (t < 15) STAGE(cur ^ 1, (t + 1) * 64);   // hides under compute(t)

    f32x16 sc[2];
#pragma unroll
    for (int f = 0; f < 2; ++f)
#pragma unroll
      for (int r = 0; r < 16; ++r) sc[f][r] = -m_run;
    __builtin_amdgcn_s_setprio(1);
    QKT(sc, cur);
    __builtin_amdgcn_s_setprio(0);

#pragma unroll
    for (int f = 0; f < 2; ++f)
#pragma unroll
      for (int r = 0; r < 16; ++r)
        sc[f][r] = __builtin_amdgcn_exp2f(sc[f][r]);

    float pm;
    MAXTREE(pm, sc);
    if (__any(pm > 2048.f)) {
      float pmx = fmaxf(pm, 1.0f);
      float scl = 1.0f / pmx;
      m_run += __builtin_amdgcn_logf(pmx);   // v_log_f32 = log2 (exp2 domain)
      l_run *= scl;
#pragma unroll
      for (int f = 0; f < 2; ++f)
#pragma unroll
        for (int r = 0; r < 16; ++r) sc[f][r] *= scl;
#pragma unroll
      for (int df = 0; df < 2; ++df)
#pragma unroll
        for (int i = 0; i < 16; ++i) O[df][i] *= scl;
    }

    float rs;
    ROWSUM(rs, sc);
    l_run += rs;
    PFBUILD(sc);
    __builtin_amdgcn_s_setprio(1);
    PVT(cur);
    __builtin_amdgcn_s_setprio(0);

    asm volatile("s_waitcnt vmcnt(0)" ::: "memory");
    __builtin_amdgcn_sched_barrier(0);
    __builtin_amdgcn_s_barrier();
  }

  // ---- epilogue: relu(O/l) -> fp32 [B,S,E]
  float inv = 1.0f / l_run;
  int s = q0 + cq;
  float* orow = out + ((size_t)bb * S_ + s) * E_ + hd * 64;
#pragma unroll
  for (int df = 0; df < 2; ++df)
#pragma unroll
    for (int g = 0; g < 4; ++g) {
      f32x4 vv;
#pragma unroll
      for (int j = 0; j < 4; ++j)
        vv[j] = fmaxf(O[df][4 * g + j] * inv, 0.f);
      *(f32x4*)&orow[df * 32 + 8 * g + 4 * h] = vv;
    }
}

// ---------------------------------------------------------------------------
// Launcher. Workspace ~70 MB:
//  Wq,Wk,Wv 3x2MB @0; Xf @6M; Qf @22M; Kf @38M; Vt @54M
// ---------------------------------------------------------------------------
extern "C" void kernel_launch(void* const* d_in, const int* in_sizes, int n_in,
                              void* d_out, int out_size, void* d_ws, size_t ws_size,
                              hipStream_t stream) {
  const float* X  = (const float*)d_in[0];
  const float* Wq = (const float*)d_in[1];
  const float* Wk = (const float*)d_in[2];
  const float* Wv = (const float*)d_in[3];
  float* out = (float*)d_out;
  char* ws = (char*)d_ws;

  const size_t WSZ = (size_t)E_ * E_ * sizeof(f16);   // 2 MB
  const size_t QSZ = (size_t)M_ * E_ * sizeof(f16);   // 16 MB
  f16* Wqf = (f16*)(ws);
  f16* Wkf = (f16*)(ws + WSZ);
  f16* Wvf = (f16*)(ws + 2 * WSZ);
  char* p = ws + 3 * WSZ;
  f16* Xf = (f16*)(p);
  f16* Qf = (f16*)(p + QSZ);
  f16* Kf = (f16*)(p + 2 * QSZ);
  f16* Vt = (f16*)(p + 3 * QSZ);

  prep_kernel<<<4864, 256, 0, stream>>>(X, Wq, Wk, Wv, Xf, Wqf, Wkf, Wvf);

  gemm_qkv_kernel<<<1536, 256, 0, stream>>>(
      Xf, Wqf, Wkf, Wvf, Qf, Kf, Vt);

  attn_kernel<<<1024, 256, 0, stream>>>(Qf, Kf, Vt, out);
}